// Round 7
// baseline (116.892 us; speedup 1.0000x reference)
//
#include <hip/hip_runtime.h>
#include <math.h>

#define NQ   16
#define NB   512
#define PI_F 3.14159265358979323846f
#define BSTR 8192          // c32 stride per batch in ws
#define ATOF 4096          // AT offset within batch slab
#define A0OF 7680
#define A15OF 7696

typedef float2 c32;

__device__ __forceinline__ c32 cmul(c32 a, c32 b) {
    return make_float2(a.x*b.x - a.y*b.y, a.x*b.y + a.y*b.x);
}
__device__ __forceinline__ c32 cfma_(c32 a, c32 b, c32 acc) {
    acc.x = fmaf(a.x, b.x, fmaf(-a.y, b.y, acc.x));
    acc.y = fmaf(a.x, b.y, fmaf( a.y, b.x, acc.y));
    return acc;
}
__device__ __forceinline__ c32 cfmaConjA(c32 a, c32 b, c32 acc) {
    acc.x = fmaf(a.x, b.x, fmaf( a.y, b.y, acc.x));
    acc.y = fmaf(a.x, b.y, fmaf(-a.y, b.x, acc.y));
    return acc;
}
__device__ __forceinline__ c32 cmulConjA(c32 a, c32 b) {
    return cfmaConjA(a, b, make_float2(0.f, 0.f));
}
__device__ __forceinline__ c32 conjc(c32 a){ return make_float2(a.x, -a.y); }
__device__ __forceinline__ c32 cadd(c32 a, c32 b){ return make_float2(a.x+b.x, a.y+b.y); }

// ===========================================================================
// Kernel 1: per-batch MPS tensor build -> ws.  One wave per batch element.
// Layout per batch (c32 slab of BSTR):
//   A   [site0..13][a*16 + i*8 + r]   (row-major, R-chain reads rows)
//   AT  at +ATOF   [(i*8+r)*16 + a]   (transposed, L-chain reads rows)
//   A0  at +A0OF   [i*8+r]
//   A15 at +A15OF  [a*2+i]
// wv(q,k,i) depends only on i^k  ->  fq[q*2 + (i^k)]  (2 values/site).
// ===========================================================================
__global__ __launch_bounds__(64)
void pqc_build_kernel(const float* __restrict__ ctx,
                      const float* __restrict__ Wm,
                      const float* __restrict__ bias,
                      const float* __restrict__ params,
                      c32* __restrict__ ws)
{
    __shared__ c32 Ug[256];
    __shared__ c32 fq[32];

    const int b = blockIdx.x;
    const int t = threadIdx.x;          // 0..63 ; gate (l,q) = (t>>4, t&15)

    c32 u00,u01,u10,u11;
    {
        const float a  = params[t*3 + 0];
        const float bb = params[t*3 + 1];
        const float c  = params[t*3 + 2];
        const float ha = 0.5f*a, hb = 0.5f*bb, hc = 0.5f*c;
        const float ca = cosf(ha), sa = sinf(ha);
        const float cb = cosf(hb), sb = sinf(hb);
        const float cz = cosf(hc), sz = sinf(hc);
        const c32 m00 = make_float2( cb*ca,  sb*sa);
        const c32 m01 = make_float2(-sb*ca, -cb*sa);
        const c32 m10 = make_float2( sb*ca, -cb*sa);
        const c32 m11 = make_float2( cb*ca, -sb*sa);
        const c32 e0 = make_float2(cz, -sz);
        const c32 e1 = make_float2(cz,  sz);
        u00 = cmul(e0, m00); u01 = cmul(e0, m01);
        u10 = cmul(e1, m10); u11 = cmul(e1, m11);
        Ug[t*4+0]=u00; Ug[t*4+1]=u01; Ug[t*4+2]=u10; Ug[t*4+3]=u11;
    }
    {   // angle dot: q = t&15, segment t>>4 (64 floats each)
        const int q = t & 15, seg = t >> 4;
        const float4* c4 = (const float4*)(ctx + (size_t)b*256);
        const float4* w4 = (const float4*)(Wm  + (size_t)q*256);
        float s = 0.f;
        #pragma unroll
        for (int j = 0; j < 16; ++j) {
            const float4 x = c4[seg*16 + j], y = w4[seg*16 + j];
            s = fmaf(x.x,y.x, fmaf(x.y,y.y, fmaf(x.z,y.z, fmaf(x.w,y.w, s))));
        }
        s += __shfl_xor(s, 16);
        s += __shfl_xor(s, 32);
        if (seg == 0) {      // lane t==q holds U0q in u00..u11
            const float ang = PI_F * tanhf(s + bias[q]);
            const float h = 0.5f*ang, ch = cosf(h), sh = sinf(h);
            fq[q*2+0] = make_float2(u00.x*ch + u01.y*sh, u00.y*ch - u01.x*sh);
            fq[q*2+1] = make_float2(u10.x*ch + u11.y*sh, u10.y*ch - u11.x*sh);
        }
    }
    __syncthreads();

    c32* W = ws + (size_t)b * BSTR;
    for (int q = 1; q <= 14; ++q) {
        const int base = (q-1)*256;
        #pragma unroll
        for (int rep = 0; rep < 4; ++rep) {
            const int idx = rep*64 + t;
            {   // row-major copy: idx = a*16 + i*8 + r
                const int a = idx>>4, i = (idx>>3)&1, r = idx&7;
                const int m0=r&1, m1=(r>>1)&1, m2=r>>2;
                const int k0=a&1, k1=(a>>1)&1, k2=(a>>2)&1, k3=a>>3;
                const c32 u3 = Ug[((48+q)<<2) + ((i ^k3)<<1) + m2];
                const c32 u2 = Ug[((32+q)<<2) + ((m2^k2)<<1) + m1];
                const c32 u1 = Ug[((16+q)<<2) + ((m1^k1)<<1) + m0];
                W[base + idx] = cmul(cmul(u3,u2), cmul(u1, fq[2*q + (k0^m0)]));
            }
            {   // transposed copy: idx = (i*8+r)*16 + a
                const int a = idx&15, ir = idx>>4;
                const int i = ir>>3, r = ir&7;
                const int m0=r&1, m1=(r>>1)&1, m2=r>>2;
                const int k0=a&1, k1=(a>>1)&1, k2=(a>>2)&1, k3=a>>3;
                const c32 u3 = Ug[((48+q)<<2) + ((i ^k3)<<1) + m2];
                const c32 u2 = Ug[((32+q)<<2) + ((m2^k2)<<1) + m1];
                const c32 u1 = Ug[((16+q)<<2) + ((m1^k1)<<1) + m0];
                W[ATOF + base + idx] = cmul(cmul(u3,u2), cmul(u1, fq[2*q + (k0^m0)]));
            }
        }
    }
    if (t < 16) {    // site 0: i*8+r
        const int i = t>>3, r = t&7;
        const int m0=r&1, m1=(r>>1)&1, m2=r>>2;
        const c32 u3 = Ug[(48<<2) + (i <<1) + m2];
        const c32 u2 = Ug[(32<<2) + (m2<<1) + m1];
        const c32 u1 = Ug[(16<<2) + (m1<<1) + m0];
        W[A0OF + t] = cmul(cmul(u3,u2), cmul(u1, fq[m0]));
    }
    if (t >= 32 && t < 64) {   // site 15 dense: a*2+i
        const int idx = t-32, aa = idx>>1, ii = idx&1;
        const int K0=aa&1, K1=(aa>>1)&1, K2=(aa>>2)&1, K3=aa>>3;
        c32 y1[2], y2[2];
        #pragma unroll
        for (int j1 = 0; j1 < 2; ++j1) {
            const int rr = (j1 ^ K1) << 1;
            y1[j1] = cfma_(Ug[((16+15)<<2)+rr], fq[30 + K0],
                     cmul (Ug[((16+15)<<2)+rr+1], fq[30 + (K0^1)]));
        }
        #pragma unroll
        for (int j2 = 0; j2 < 2; ++j2) {
            const int rr = (j2 ^ K2) << 1;
            y2[j2] = cfma_(Ug[((32+15)<<2)+rr], y1[0],
                     cmul (Ug[((32+15)<<2)+rr+1], y1[1]));
        }
        const int rr = (ii ^ K3) << 1;
        W[A15OF + (aa<<1) + ii] = cfma_(Ug[((48+15)<<2)+rr], y2[0],
                                  cmul (Ug[((48+15)<<2)+rr+1], y2[1]));
    }
}

// ===========================================================================
// Kernel 2: env sweep. LDS = envs only (40.06 KB -> 4 blocks/CU). Site
// tensors stream from ws via L1/L2 with register prefetch one phase ahead.
// ===========================================================================
__global__ __launch_bounds__(256, 4)
void pqc_sweep_kernel(const c32* __restrict__ ws, float* __restrict__ out)
{
    __shared__ c32 Renv[15][144];   // R_q: m*72 + bl*9 + bp
    __shared__ c32 Ssto[15][144];   // S_q: i*72 + bl*9 + bp
    __shared__ c32 TRb[272];        // bb*17 + i*8 + gp
    __shared__ c32 TLT[272];        // (i*8+bp)*17 + a
    __shared__ c32 Lbuf[144];       // running L env

    const int b = blockIdx.x;
    const int t = threadIdx.x;
    const c32* Ab  = ws + (size_t)b * BSTR;   // row-major sites
    const c32* ATb = Ab + ATOF;               // transposed sites
    const c32* A0  = Ab + A0OF;
    const c32* A15 = Ab + A15OF;

    // thread roles (identical to round-5 mapping)
    const int bbR = t >> 3, iR = (t >> 2) & 1, gp0 = (t & 3) * 2;
    const int uL  = t - 128;
    const int aL  = uL >> 3, iL = (uL >> 2) & 1, bp0 = (uL & 3) * 2;
    const int mL  = aL >> 3, alL = aL & 7;
    const int m2  = (t >> 6) & 1, bl2 = (t >> 3) & 7, bp2 = t & 7;
    const int i2L = uL >> 6;

    c32 aP1[8], sA0[8], sA1[8], pf2[16];

    // ---- init step 0 + prologue prefetch (s=1) ------------------------------
    if (t < 128) {
        const int m = t>>6, bl = (t>>3)&7, bp = t&7;
        c32 acc = cmulConjA(A15[((m<<3)+bl)<<1],       A15[((m<<3)+bp)<<1]);
        acc     = cfmaConjA(A15[(((m<<3)+bl)<<1) + 1], A15[(((m<<3)+bp)<<1) + 1], acc);
        Renv[14][m*72 + bl*9 + bp] = acc;
        const c32* Ap = Ab + 13*256;          // site 14 (s=1)
        #pragma unroll
        for (int g = 0; g < 8; ++g) aP1[g] = Ap[bbR*16 + iR*8 + g];
    } else {
        const int i = uL>>6, bl = (uL>>3)&7, bp = uL&7;
        const c32 sv = cmulConjA(A0[(i<<3)+bl], A0[(i<<3)+bp]);
        Ssto[0][i*72 + bl*9 + bp] = sv;
        Lbuf   [i*72 + bl*9 + bp] = sv;
        const c32* AsT = ATb;                 // site 1 (s=1)
        #pragma unroll
        for (int g = 0; g < 8; ++g) {
            sA0[g] = AsT[(iL*8 + bp0    )*16 + mL*8 + g];
            sA1[g] = AsT[(iL*8 + bp0 + 1)*16 + mL*8 + g];
        }
    }
    __syncthreads();

    // ---- merged sweep: R chain (waves 0-1), L chain (waves 2-3) -------------
    for (int s = 1; s <= 14; ++s) {
        const c32* Ap  = Ab  + (14 - s)*256;  // site 15-s, rows
        const c32* AsT = ATb + (s - 1)*256;   // site s, transposed

        if (t < 128) {
            // phase1-R: TR[bb,i,gp] = conj( sum_g Ap[bb,i,g] * Rn[i][gp,g] )
            const c32* RnB = Renv[15-s] + iR*72 + gp0*9;
            c32 x0 = make_float2(0.f,0.f), x1 = x0;
            #pragma unroll
            for (int g = 0; g < 8; ++g) {
                x0 = cfma_(aP1[g], RnB[g],   x0);
                x1 = cfma_(aP1[g], RnB[9+g], x1);
            }
            TRb[bbR*17 + iR*8 + gp0]     = conjc(x0);
            TRb[bbR*17 + iR*8 + gp0 + 1] = conjc(x1);
            #pragma unroll
            for (int k = 0; k < 16; ++k) pf2[k] = Ap[(m2*8+bp2)*16 + k];
        } else {
            // phase1-L: TL[a,i,bp] = sum_g L[m][al,g] * A[(m,g),i,bp]
            const c32* Lr = Lbuf + mL*72 + alL*9;
            c32 x0 = make_float2(0.f,0.f), x1 = x0;
            #pragma unroll
            for (int g = 0; g < 8; ++g) {
                const c32 lv = Lr[g];
                x0 = cfma_(lv, sA0[g], x0);
                x1 = cfma_(lv, sA1[g], x1);
            }
            TLT[(iL*8 + bp0    )*17 + aL] = x0;
            TLT[(iL*8 + bp0 + 1)*17 + aL] = x1;
            #pragma unroll
            for (int k = 0; k < 16; ++k) pf2[k] = AsT[(i2L*8+bl2)*16 + k];
        }
        __syncthreads();

        if (t < 128) {
            // phase2-R: R_new[m][bl,bp] = sum_k TR[(m,bl),k] * A[(m,bp),k]
            const c32* trR = TRb + (m2*8 + bl2)*17;
            c32 r0 = make_float2(0.f,0.f), r1 = r0;
            #pragma unroll
            for (int k = 0; k < 16; k += 2) {
                r0 = cfma_(trR[k],   pf2[k],   r0);
                r1 = cfma_(trR[k+1], pf2[k+1], r1);
            }
            Renv[14-s][m2*72 + bl2*9 + bp2] = cadd(r0, r1);
            if (s < 14) {
                const c32* ApN = Ab + (13 - s)*256;   // site 14-s
                #pragma unroll
                for (int g = 0; g < 8; ++g) aP1[g] = ApN[bbR*16 + iR*8 + g];
            }
        } else {
            // phase2-L: S[i][bl,bp] = sum_a conj(A[a,i,bl]) * TL[(i,bp),a]
            const c32* tlR = TLT + (i2L*8 + bp2)*17;
            c32 s0 = make_float2(0.f,0.f), s1 = s0;
            #pragma unroll
            for (int k = 0; k < 16; k += 2) {
                s0 = cfmaConjA(pf2[k],   tlR[k],   s0);
                s1 = cfmaConjA(pf2[k+1], tlR[k+1], s1);
            }
            const c32 sv = cadd(s0, s1);
            Ssto[s][i2L*72 + bl2*9 + bp2] = sv;
            Lbuf   [i2L*72 + bl2*9 + bp2] = sv;
            if (s < 14) {
                const c32* AsN = ATb + s*256;         // site s+1
                #pragma unroll
                for (int g = 0; g < 8; ++g) {
                    sA0[g] = AsN[(iL*8 + bp0    )*16 + mL*8 + g];
                    sA1[g] = AsN[(iL*8 + bp0 + 1)*16 + mL*8 + g];
                }
            }
        }
        __syncthreads();
    }

    // ---- Z phase ------------------------------------------------------------
    {
        const int q = t >> 4, g = t & 15;
        float val = 0.f;
        if (q < 15) {
            const int i = g>>3, bl = g&7;
            const float sign = i ? -1.f : 1.f;
            const c32* Sq = &Ssto[q][i*72 + bl*9];
            const c32* Rq = &Renv[q][i*72 + bl*9];
            #pragma unroll
            for (int j = 0; j < 8; ++j)
                val += sign * (Sq[j].x*Rq[j].x - Sq[j].y*Rq[j].y);
        } else {
            const int m = g>>3, al = g&7;
            const c32 a0 = A15[((m*8+al)<<1) + 0];
            const c32 a1 = A15[((m*8+al)<<1) + 1];
            #pragma unroll
            for (int j = 0; j < 8; ++j) {
                c32 d = cmulConjA(a0, A15[((m*8+j)<<1) + 0]);
                const c32 d1 = cmulConjA(a1, A15[((m*8+j)<<1) + 1]);
                d.x -= d1.x; d.y -= d1.y;
                const c32 Lv = Lbuf[m*72 + al*9 + j];
                val += Lv.x*d.x - Lv.y*d.y;
            }
        }
        #pragma unroll
        for (int mm = 8; mm; mm >>= 1) val += __shfl_xor(val, mm);
        if (g == 0) out[b*NQ + q] = val;
    }
}

extern "C" void kernel_launch(void* const* d_in, const int* in_sizes, int n_in,
                              void* d_out, int out_size, void* d_ws, size_t ws_size,
                              hipStream_t stream) {
    const float* ctx    = (const float*)d_in[0];   // [512,256]
    const float* Wm     = (const float*)d_in[1];   // [16,256]
    const float* bias   = (const float*)d_in[2];   // [16]
    const float* params = (const float*)d_in[3];   // [4,16,3]
    float* out = (float*)d_out;                    // [512,16]
    c32* ws = (c32*)d_ws;                          // >= 512*8192*8 B = 33.6 MB
    (void)in_sizes; (void)n_in; (void)out_size; (void)ws_size;
    pqc_build_kernel<<<NB, 64, 0, stream>>>(ctx, Wm, bias, params, ws);
    pqc_sweep_kernel<<<NB, 256, 0, stream>>>(ws, out);
}

// Round 8
// 78.952 us; speedup vs baseline: 1.4806x; 1.4806x over previous
//
#include <hip/hip_runtime.h>
#include <math.h>

#define NQ   16
#define NB   512
#define NTH  128
#define PI_F 3.14159265358979323846f

typedef float2 c32;

__device__ __forceinline__ c32 cmul(c32 a, c32 b) {
    return make_float2(a.x*b.x - a.y*b.y, a.x*b.y + a.y*b.x);
}
__device__ __forceinline__ c32 cfma_(c32 a, c32 b, c32 acc) {
    acc.x = fmaf(a.x, b.x, fmaf(-a.y, b.y, acc.x));
    acc.y = fmaf(a.x, b.y, fmaf( a.y, b.x, acc.y));
    return acc;
}
__device__ __forceinline__ c32 cfmaConjA(c32 a, c32 b, c32 acc) {
    acc.x = fmaf(a.x, b.x, fmaf( a.y, b.y, acc.x));
    acc.y = fmaf(a.x, b.y, fmaf(-a.y, b.x, acc.y));
    return acc;
}
__device__ __forceinline__ c32 cmulConjA(c32 a, c32 b) {
    return cfmaConjA(a, b, make_float2(0.f, 0.f));
}
__device__ __forceinline__ c32 conjc(c32 a){ return make_float2(a.x, -a.y); }
__device__ __forceinline__ c32 cadd(c32 a, c32 b){ return make_float2(a.x+b.x, a.y+b.y); }

// Compact MPS (right-bond top bit == physical index). Envs Hermitian on two
// diagonal 8x8 blocks (proven by induction: R_new = A^H R A, S_new = A^H L A).
// One FULL WAVE per chain: wave0 = R (TRb/Renv private), wave1 = L
// (TLT/Lbuf/Ssto private). All sweep dependencies intra-wave -> ZERO barriers
// in the 14-step loop. Stage1 2x2 register tile (8 c32/output); stage2
// lower-triangle only + conj mirror writes (44% fewer reads).

__global__ __launch_bounds__(NTH)
void pqc_mps_kernel(const float* __restrict__ ctx,
                    const float* __restrict__ Wm,
                    const float* __restrict__ bias,
                    const float* __restrict__ params,
                    float* __restrict__ out)
{
    __shared__ c32 Ac[14*272];      // sites 1..14: (q-1)*272 + a*17 + i*8 + r
    __shared__ c32 A0c[16];         // i*8 + r
    __shared__ c32 A15v[32];        // a*2 + i
    __shared__ c32 Renv[15*144];    // R_q: q*144 + m*72 + bl*9 + bp   (wave0)
    __shared__ c32 Ssto[15*144];    // S_q: q*144 + i*72 + bl*9 + bp   (wave1)
    __shared__ c32 TRb[272];        // bb*17 + i*8 + gp                (wave0)
    __shared__ c32 TLT[272];        // (i*8+bp)*17 + a                 (wave1)
    __shared__ c32 Lbuf[144];       // running L env                   (wave1)
    __shared__ c32 Ug[256];         // fused RZ*RY*RX per (l,q)
    __shared__ c32 wv[64];          // w[q,k,i]
    __shared__ float angles[NQ];

    const int b = blockIdx.x;
    const int t = threadIdx.x;
    const int lane = t & 63;

    // ---- build A: encoding angles (8 lanes per q) ---------------------------
    {
        const int q = t >> 3, g = t & 7;
        const float4* c4 = (const float4*)(ctx + (size_t)b * 256);
        const float4* w4 = (const float4*)(Wm  + (size_t)q * 256);
        float s = 0.f;
        #pragma unroll
        for (int j = 0; j < 8; ++j) {
            const float4 x = c4[g + 8*j], y = w4[g + 8*j];
            s = fmaf(x.x,y.x, fmaf(x.y,y.y, fmaf(x.z,y.z, fmaf(x.w,y.w, s))));
        }
        s += __shfl_xor(s, 4); s += __shfl_xor(s, 2); s += __shfl_xor(s, 1);
        if (g == 0) angles[q] = PI_F * tanhf(s + bias[q]);
    }
    if (t < 64) {  // U = RZ*RY*RX per (l,q) = (t>>4, t&15)
        const float a  = params[t*3 + 0];
        const float bb = params[t*3 + 1];
        const float c  = params[t*3 + 2];
        const float ha = 0.5f*a, hb = 0.5f*bb, hc = 0.5f*c;
        const float ca = cosf(ha), sa = sinf(ha);
        const float cb = cosf(hb), sb = sinf(hb);
        const float cz = cosf(hc), sz = sinf(hc);
        const c32 m00 = make_float2( cb*ca,  sb*sa);
        const c32 m01 = make_float2(-sb*ca, -cb*sa);
        const c32 m10 = make_float2( sb*ca, -cb*sa);
        const c32 m11 = make_float2( cb*ca, -sb*sa);
        const c32 e0 = make_float2(cz, -sz);
        const c32 e1 = make_float2(cz,  sz);
        Ug[t*4 + 0] = cmul(e0, m00);
        Ug[t*4 + 1] = cmul(e0, m01);
        Ug[t*4 + 2] = cmul(e1, m10);
        Ug[t*4 + 3] = cmul(e1, m11);
    }
    __syncthreads();

    if (t < 64) {  // w[q,k,i] = U0q[i^k,:]·(cos h, -i sin h)
        const int q = t >> 2, k = (t>>1)&1, i = t&1;
        const float h = 0.5f * angles[q];
        const float ch = cosf(h), sh = sinf(h);
        const int r0 = (i ^ k) << 1;
        const c32 u0 = Ug[(q<<2) + r0];
        const c32 u1 = Ug[(q<<2) + r0 + 1];
        wv[t] = make_float2(u0.x*ch + u1.y*sh, u0.y*ch - u1.x*sh);
    }
    __syncthreads();

    // ---- build compact MPS tensors ------------------------------------------
    {
        for (int q = 1; q <= 14; ++q) {
            #pragma unroll
            for (int h = 0; h < 2; ++h) {
                const int idx = t + 128*h;
                const int r = idx & 7, i = (idx>>3)&1, a = idx>>4;
                const int m0 = r&1, m1 = (r>>1)&1, m2 = r>>2;
                const int k0 = a&1, k1 = (a>>1)&1, k2 = (a>>2)&1, k3 = a>>3;
                const c32 u3 = Ug[((48+q)<<2) + ((i ^k3)<<1) + m2];
                const c32 u2 = Ug[((32+q)<<2) + ((m2^k2)<<1) + m1];
                const c32 u1 = Ug[((16+q)<<2) + ((m1^k1)<<1) + m0];
                const c32 ww = wv[(q<<2) + (k0<<1) + m0];
                Ac[(q-1)*272 + a*17 + i*8 + r] = cmul(cmul(u3, u2), cmul(u1, ww));
            }
        }
        if (t < 16) {  // site 0
            const int i = t>>3, r = t&7;
            const int m0 = r&1, m1 = (r>>1)&1, m2 = r>>2;
            const c32 u3 = Ug[(48<<2) + (i <<1) + m2];
            const c32 u2 = Ug[(32<<2) + (m2<<1) + m1];
            const c32 u1 = Ug[(16<<2) + (m1<<1) + m0];
            A0c[t] = cmul(cmul(u3, u2), cmul(u1, wv[m0]));
        }
        if (t >= 64 && t < 96) {  // site 15 dense
            const int idx = t - 64, aa = idx >> 1, ii = idx & 1;
            const int K0 = aa&1, K1 = (aa>>1)&1, K2 = (aa>>2)&1, K3 = aa>>3;
            c32 y1[2], y2[2];
            #pragma unroll
            for (int j1 = 0; j1 < 2; ++j1) {
                const int rr = (j1 ^ K1) << 1;
                y1[j1] = cfma_(Ug[((16+15)<<2)+rr], wv[60 + (K0<<1)],
                         cmul (Ug[((16+15)<<2)+rr+1], wv[60 + (K0<<1) + 1]));
            }
            #pragma unroll
            for (int j2 = 0; j2 < 2; ++j2) {
                const int rr = (j2 ^ K2) << 1;
                y2[j2] = cfma_(Ug[((32+15)<<2)+rr], y1[0],
                         cmul (Ug[((32+15)<<2)+rr+1], y1[1]));
            }
            const int rr = (ii ^ K3) << 1;
            A15v[(aa<<1)+ii] = cfma_(Ug[((48+15)<<2)+rr], y2[0],
                               cmul (Ug[((48+15)<<2)+rr+1], y2[1]));
        }
    }
    __syncthreads();

    // ---- Hermitian job decode (once): job1 = lane; job2 (lanes<8) = (1,7,lane)
    int blJ = 0, bpJ, mJ;
    {
        const int r = (lane < 36) ? lane : lane - 36;
        mJ = (lane >= 36) ? 1 : 0;
        while ((blJ+1)*(blJ+2)/2 <= r) ++blJ;
        bpJ = r - blJ*(blJ+1)/2;
    }
    const bool has2 = (lane < 8);

    if (t < 64) {
        // ================= wave 0: R chain (no barriers) =====================
        const int bbp = lane>>3, iS = (lane>>2)&1, gpp = lane&3;
        const int bb0 = 2*bbp, bb1 = bb0+1, gq0 = 2*gpp, gq1 = gq0+1;

        {   // init R_14 from A15 (Hermitian jobs)
            c32 acc = make_float2(0.f,0.f);
            #pragma unroll
            for (int i = 0; i < 2; ++i)
                acc = cfmaConjA(A15v[(mJ*8+blJ)*2+i], A15v[(mJ*8+bpJ)*2+i], acc);
            Renv[14*144 + mJ*72 + blJ*9 + bpJ] = acc;
            if (blJ != bpJ) Renv[14*144 + mJ*72 + bpJ*9 + blJ] = conjc(acc);
            if (has2) {
                c32 a2 = make_float2(0.f,0.f);
                #pragma unroll
                for (int i = 0; i < 2; ++i)
                    a2 = cfmaConjA(A15v[(8+7)*2+i], A15v[(8+lane)*2+i], a2);
                Renv[14*144 + 72 + 7*9 + lane] = a2;
                if (lane != 7) Renv[14*144 + 72 + lane*9 + 7] = conjc(a2);
            }
        }
        for (int s = 1; s <= 14; ++s) {
            const c32* Ap = Ac + (14-s)*272;
            const c32* Rn = Renv + (15-s)*144;
            c32*       Ro = Renv + (14-s)*144;
            // stage1: 2x2 tile -> 4 TR outputs
            c32 aA[8], aB[8], rA[8], rB[8];
            #pragma unroll
            for (int g = 0; g < 8; ++g) {
                aA[g] = Ap[bb0*17 + iS*8 + g];
                aB[g] = Ap[bb1*17 + iS*8 + g];
                rA[g] = Rn[iS*72 + gq0*9 + g];
                rB[g] = Rn[iS*72 + gq1*9 + g];
            }
            c32 t00=make_float2(0.f,0.f), t01=t00, t10=t00, t11=t00;
            #pragma unroll
            for (int g = 0; g < 8; ++g) {
                t00 = cfma_(aA[g], rA[g], t00); t01 = cfma_(aA[g], rB[g], t01);
                t10 = cfma_(aB[g], rA[g], t10); t11 = cfma_(aB[g], rB[g], t11);
            }
            TRb[bb0*17 + iS*8 + gq0] = conjc(t00);
            TRb[bb0*17 + iS*8 + gq1] = conjc(t01);
            TRb[bb1*17 + iS*8 + gq0] = conjc(t10);
            TRb[bb1*17 + iS*8 + gq1] = conjc(t11);
            // stage2: Hermitian jobs
            {
                const c32* tr = TRb + (mJ*8+blJ)*17;
                const c32* ap = Ap  + (mJ*8+bpJ)*17;
                c32 r0 = make_float2(0.f,0.f), r1 = r0;
                #pragma unroll
                for (int k = 0; k < 16; k += 2) {
                    r0 = cfma_(tr[k],   ap[k],   r0);
                    r1 = cfma_(tr[k+1], ap[k+1], r1);
                }
                const c32 acc = cadd(r0, r1);
                Ro[mJ*72 + blJ*9 + bpJ] = acc;
                if (blJ != bpJ) Ro[mJ*72 + bpJ*9 + blJ] = conjc(acc);
            }
            if (has2) {
                const c32* tr = TRb + (8+7)*17;
                const c32* ap = Ap  + (8+lane)*17;
                c32 r0 = make_float2(0.f,0.f), r1 = r0;
                #pragma unroll
                for (int k = 0; k < 16; k += 2) {
                    r0 = cfma_(tr[k],   ap[k],   r0);
                    r1 = cfma_(tr[k+1], ap[k+1], r1);
                }
                const c32 acc = cadd(r0, r1);
                Ro[72 + 7*9 + lane] = acc;
                if (lane != 7) Ro[72 + lane*9 + 7] = conjc(acc);
            }
        }
    } else {
        // ================= wave 1: L chain (no barriers) =====================
        const int ap_ = lane>>3, iS = (lane>>2)&1, bpp = lane&3;
        const int a0_ = 2*ap_, a1_ = a0_+1, bq0 = 2*bpp, bq1 = bq0+1;
        const int mS = ap_>>2, al0 = a0_&7, al1 = a1_&7;

        {   // init S_0 from A0 (Hermitian jobs; mJ plays the i-index role)
            const c32 sv = cmulConjA(A0c[mJ*8+blJ], A0c[mJ*8+bpJ]);
            Ssto[mJ*72 + blJ*9 + bpJ] = sv;
            Lbuf[mJ*72 + blJ*9 + bpJ] = sv;
            if (blJ != bpJ) {
                const c32 cs = conjc(sv);
                Ssto[mJ*72 + bpJ*9 + blJ] = cs;
                Lbuf[mJ*72 + bpJ*9 + blJ] = cs;
            }
            if (has2) {
                const c32 s2 = cmulConjA(A0c[8+7], A0c[8+lane]);
                Ssto[72 + 7*9 + lane] = s2;
                Lbuf[72 + 7*9 + lane] = s2;
                if (lane != 7) {
                    const c32 cs = conjc(s2);
                    Ssto[72 + lane*9 + 7] = cs;
                    Lbuf[72 + lane*9 + 7] = cs;
                }
            }
        }
        for (int s = 1; s <= 14; ++s) {
            const c32* As = Ac + (s-1)*272;
            c32*       So = Ssto + s*144;
            // stage1: 2x2 tile -> 4 TL outputs (stored transposed)
            c32 lA[8], lB[8], c0v[8], c1v[8];
            #pragma unroll
            for (int g = 0; g < 8; ++g) {
                lA[g]  = Lbuf[mS*72 + al0*9 + g];
                lB[g]  = Lbuf[mS*72 + al1*9 + g];
                c0v[g] = As[(mS*8+g)*17 + iS*8 + bq0];
                c1v[g] = As[(mS*8+g)*17 + iS*8 + bq1];
            }
            c32 t00=make_float2(0.f,0.f), t01=t00, t10=t00, t11=t00;
            #pragma unroll
            for (int g = 0; g < 8; ++g) {
                t00 = cfma_(lA[g], c0v[g], t00); t01 = cfma_(lA[g], c1v[g], t01);
                t10 = cfma_(lB[g], c0v[g], t10); t11 = cfma_(lB[g], c1v[g], t11);
            }
            TLT[(iS*8 + bq0)*17 + a0_] = t00;
            TLT[(iS*8 + bq1)*17 + a0_] = t01;
            TLT[(iS*8 + bq0)*17 + a1_] = t10;
            TLT[(iS*8 + bq1)*17 + a1_] = t11;
            // stage2: Hermitian jobs (i = mJ)
            {
                const c32* tl = TLT + (mJ*8+bpJ)*17;
                c32 s0 = make_float2(0.f,0.f), s1 = s0;
                #pragma unroll
                for (int k = 0; k < 16; k += 2) {
                    s0 = cfmaConjA(As[ k   *17 + mJ*8 + blJ], tl[k],   s0);
                    s1 = cfmaConjA(As[(k+1)*17 + mJ*8 + blJ], tl[k+1], s1);
                }
                const c32 acc = cadd(s0, s1);
                So[mJ*72 + blJ*9 + bpJ] = acc;
                Lbuf[mJ*72 + blJ*9 + bpJ] = acc;
                if (blJ != bpJ) {
                    const c32 cs = conjc(acc);
                    So[mJ*72 + bpJ*9 + blJ] = cs;
                    Lbuf[mJ*72 + bpJ*9 + blJ] = cs;
                }
            }
            if (has2) {
                const c32* tl = TLT + (8+lane)*17;
                c32 s0 = make_float2(0.f,0.f), s1 = s0;
                #pragma unroll
                for (int k = 0; k < 16; k += 2) {
                    s0 = cfmaConjA(As[ k   *17 + 8 + 7], tl[k],   s0);
                    s1 = cfmaConjA(As[(k+1)*17 + 8 + 7], tl[k+1], s1);
                }
                const c32 acc = cadd(s0, s1);
                So[72 + 7*9 + lane] = acc;
                Lbuf[72 + 7*9 + lane] = acc;
                if (lane != 7) {
                    const c32 cs = conjc(acc);
                    So[72 + lane*9 + 7] = cs;
                    Lbuf[72 + lane*9 + 7] = cs;
                }
            }
        }
    }
    __syncthreads();

    // ---- Z phase: thread (qb, g) handles sites qb and qb+8 ------------------
    {
        const int g = t & 15, qb = t >> 4;   // qb 0..7
        #pragma unroll
        for (int h = 0; h < 2; ++h) {
            const int qq = qb + 8*h;
            float val = 0.f;
            if (qq < 15) {
                const int i = g>>3, blz = g&7;
                const float sign = i ? -1.f : 1.f;
                const c32* Sq = Ssto + qq*144 + i*72 + blz*9;
                const c32* Rq = Renv + qq*144 + i*72 + blz*9;
                #pragma unroll
                for (int j = 0; j < 8; ++j)
                    val += sign * (Sq[j].x*Rq[j].x - Sq[j].y*Rq[j].y);
            } else {
                const int m = g>>3, al = g&7;
                const c32 a0 = A15v[((m*8+al)<<1) + 0];
                const c32 a1 = A15v[((m*8+al)<<1) + 1];
                #pragma unroll
                for (int j = 0; j < 8; ++j) {
                    c32 d = cmulConjA(a0, A15v[((m*8+j)<<1) + 0]);
                    const c32 d1 = cmulConjA(a1, A15v[((m*8+j)<<1) + 1]);
                    d.x -= d1.x; d.y -= d1.y;
                    const c32 Lv = Lbuf[m*72 + al*9 + j];
                    val += Lv.x*d.x - Lv.y*d.y;
                }
            }
            val += __shfl_xor(val, 8);
            val += __shfl_xor(val, 4);
            val += __shfl_xor(val, 2);
            val += __shfl_xor(val, 1);
            if (g == 0) out[b*NQ + qq] = val;
        }
    }
}

extern "C" void kernel_launch(void* const* d_in, const int* in_sizes, int n_in,
                              void* d_out, int out_size, void* d_ws, size_t ws_size,
                              hipStream_t stream) {
    const float* ctx    = (const float*)d_in[0];   // [512,256]
    const float* Wm     = (const float*)d_in[1];   // [16,256]
    const float* bias   = (const float*)d_in[2];   // [16]
    const float* params = (const float*)d_in[3];   // [4,16,3]
    float* out = (float*)d_out;                    // [512,16]
    (void)in_sizes; (void)n_in; (void)out_size; (void)d_ws; (void)ws_size;
    pqc_mps_kernel<<<NB, NTH, 0, stream>>>(ctx, Wm, bias, params, out);
}